// Round 2
// baseline (4671.820 us; speedup 1.0000x reference)
//
#include <hip/hip_runtime.h>
#include <hip/hip_bf16.h>
#include <math.h>

// Problem constants
#define BATCH   16
#define NTOK    393            // 3*128 + 9
#define ROWS    (BATCH * NTOK) // 6288
#define DMODEL  512
#define NHEAD   8
#define DHEAD   64
#define FCDIM   2048
#define DEPTH   4
#define NPRED   20
#define ATTN_PER_LAYER ((size_t)BATCH * NHEAD * NTOK * NTOK) // 19,769,472

// ---------------------------------------------------------------------------
// Embedding: per-agent linear projections + sinusoidal PE + spec tokens
// grid: B*393 blocks, 256 threads
// ---------------------------------------------------------------------------
__global__ __launch_bounds__(256) void embed_kernel(
    const float* __restrict__ x_in, const float* __restrict__ spec,
    const float* __restrict__ Wc, const float* __restrict__ bc,
    const float* __restrict__ Wb, const float* __restrict__ bb,
    const float* __restrict__ Wt, const float* __restrict__ btg,
    const float* __restrict__ specW, const float* __restrict__ specB,
    float* __restrict__ X) {
  int bt = blockIdx.x;
  int b = bt / NTOK, t = bt % NTOK;
  int tid = threadIdx.x;
  for (int d = tid; d < DMODEL; d += 256) {
    float val;
    if (t < 384) {
      int a = t >> 7, p = t & 127;
      const float* W; const float* bias; int nf, f0;
      if (a == 0)      { W = Wc; bias = bc;  nf = 9;  f0 = 0;  }
      else if (a == 1) { W = Wb; bias = bb;  nf = 12; f0 = 9;  }
      else             { W = Wt; bias = btg; nf = 8;  f0 = 21; }
      val = bias[d];
      const float* xi = x_in + ((size_t)b * 128 + p) * 29 + f0;
      for (int f = 0; f < nf; ++f) val += xi[f] * W[f * DMODEL + d];
      // sinusoidal PE: i = even index = 2*(d>>1)
      float iv = (float)((d >> 1) << 1);
      float div = expf(-logf(10000.0f) * iv / (float)DMODEL);
      float aa = (float)a * div, tt = (float)p * div;
      val += (d & 1) ? (cosf(aa) + cosf(tt)) : (sinf(aa) + sinf(tt));
    } else {
      int f = t - 384;
      val = spec[b * 9 + f] * specW[f * DMODEL + d] + specB[f * DMODEL + d];
    }
    X[((size_t)b * NTOK + t) * DMODEL + d] = val;
  }
}

// ---------------------------------------------------------------------------
// LayerNorm over last dim (512). One block (256 thr) per row, 2 elems/thread.
// ---------------------------------------------------------------------------
__global__ __launch_bounds__(256) void ln_kernel(
    const float* __restrict__ X, const float* __restrict__ g,
    const float* __restrict__ b, float* __restrict__ Y) {
  size_t row = blockIdx.x;
  int tid = threadIdx.x;
  const float* xr = X + row * DMODEL;
  float2 v = *(const float2*)(xr + tid * 2);
  float s = v.x + v.y;
  for (int off = 32; off; off >>= 1) s += __shfl_down(s, off);
  __shared__ float red[4];
  if ((tid & 63) == 0) red[tid >> 6] = s;
  __syncthreads();
  float mu = (red[0] + red[1] + red[2] + red[3]) * (1.0f / DMODEL);
  __syncthreads();
  float dx = v.x - mu, dy = v.y - mu;
  float s2 = dx * dx + dy * dy;
  for (int off = 32; off; off >>= 1) s2 += __shfl_down(s2, off);
  if ((tid & 63) == 0) red[tid >> 6] = s2;
  __syncthreads();
  float var = (red[0] + red[1] + red[2] + red[3]) * (1.0f / DMODEL);
  float rs = rsqrtf(var + 1e-5f);
  float2 o;
  o.x = dx * rs * g[tid * 2]     + b[tid * 2];
  o.y = dy * rs * g[tid * 2 + 1] + b[tid * 2 + 1];
  *(float2*)(Y + row * DMODEL + tid * 2) = o;
}

// ---------------------------------------------------------------------------
// fp32 tiled GEMM: C[M,N] = epilogue(A[M,K] @ W[K,N]).
// 64x64 tile, BK=16, 256 threads, 4x4 per thread.
// Epilogue: optional bias add, exact GELU, residual add.
// ---------------------------------------------------------------------------
template <bool BIAS, bool RES, bool GELU_ACT>
__global__ __launch_bounds__(256) void gemm_kernel(
    const float* __restrict__ A, const float* __restrict__ W,
    const float* __restrict__ bias, const float* __restrict__ R,
    float* __restrict__ C, int M, int K, int N) {
  __shared__ float As[16][64];
  __shared__ float Bs[16][64];
  int tid = threadIdx.x;
  int bm = blockIdx.y * 64;
  int bn = blockIdx.x * 64;
  int ty = tid >> 4, tx = tid & 15;
  float acc[4][4] = {};

  int ar = tid >> 2;
  int ak = (tid & 3) << 2;
  int wc = tid & 63;
  int wk = tid >> 6;

  for (int k0 = 0; k0 < K; k0 += 16) {
    int grow = bm + ar;
    if (grow < M) {
      const float* ap = A + (size_t)grow * K + k0 + ak;
      #pragma unroll
      for (int i = 0; i < 4; ++i) As[ak + i][ar] = ap[i];
    } else {
      #pragma unroll
      for (int i = 0; i < 4; ++i) As[ak + i][ar] = 0.0f;
    }
    #pragma unroll
    for (int r = 0; r < 4; ++r)
      Bs[wk + 4 * r][wc] = W[(size_t)(k0 + wk + 4 * r) * N + bn + wc];
    __syncthreads();
    #pragma unroll
    for (int k = 0; k < 16; ++k) {
      float a[4], bfrag[4];
      #pragma unroll
      for (int i = 0; i < 4; ++i) a[i] = As[k][ty * 4 + i];
      #pragma unroll
      for (int j = 0; j < 4; ++j) bfrag[j] = Bs[k][tx * 4 + j];
      #pragma unroll
      for (int i = 0; i < 4; ++i)
        #pragma unroll
        for (int j = 0; j < 4; ++j) acc[i][j] += a[i] * bfrag[j];
    }
    __syncthreads();
  }
  #pragma unroll
  for (int i = 0; i < 4; ++i) {
    int row = bm + ty * 4 + i;
    if (row >= M) break;
    #pragma unroll
    for (int j = 0; j < 4; ++j) {
      int col = bn + tx * 4 + j;
      float v = acc[i][j];
      if (BIAS) v += bias[col];
      if (GELU_ACT) v = 0.5f * v * (1.0f + erff(v * 0.70710678118f));
      if (RES) v += R[(size_t)row * N + col];
      C[(size_t)row * N + col] = v;
    }
  }
}

// ---------------------------------------------------------------------------
// Attention scores with binary mask select: S = scale * (same-agent-block ?
// qs.ks : q.k). Writes raw scores directly into d_out attn region.
// grid: (25 i-tiles, 128 bh), 256 threads.
// ---------------------------------------------------------------------------
__global__ __launch_bounds__(256) void scores_kernel(
    const float* __restrict__ qkv, const float* __restrict__ qks,
    float* __restrict__ S) {
  int bh = blockIdx.y;
  int b = bh >> 3, hd = bh & 7;
  int i0 = blockIdx.x * 16;
  __shared__ float Q[16][64], Qs[16][64];
  __shared__ float Kt[16][65], Ks[16][65]; // +1 pad: avoid 16-way bank conflict
  int tid = threadIdx.x;
  int r = tid >> 4, d4 = (tid & 15) * 4;
  {
    int gi = i0 + r;
    if (gi < NTOK) {
      const float* qp  = qkv + ((size_t)(b * NTOK + gi)) * 1536 + hd * 64 + d4;
      const float* qsp = qks + ((size_t)(b * NTOK + gi)) * 1024 + hd * 64 + d4;
      #pragma unroll
      for (int t = 0; t < 4; ++t) { Q[r][d4 + t] = qp[t]; Qs[r][d4 + t] = qsp[t]; }
    } else {
      #pragma unroll
      for (int t = 0; t < 4; ++t) { Q[r][d4 + t] = 0.f; Qs[r][d4 + t] = 0.f; }
    }
  }
  const float scale = 0.125f; // 64^-0.5
  int ti = tid >> 4, tj = tid & 15;
  for (int j0 = 0; j0 < NTOK; j0 += 16) {
    __syncthreads();
    int gj = j0 + r;
    if (gj < NTOK) {
      const float* kp  = qkv + ((size_t)(b * NTOK + gj)) * 1536 + 512 + hd * 64 + d4;
      const float* ksp = qks + ((size_t)(b * NTOK + gj)) * 1024 + 512 + hd * 64 + d4;
      #pragma unroll
      for (int t = 0; t < 4; ++t) { Kt[r][d4 + t] = kp[t]; Ks[r][d4 + t] = ksp[t]; }
    } else {
      #pragma unroll
      for (int t = 0; t < 4; ++t) { Kt[r][d4 + t] = 0.f; Ks[r][d4 + t] = 0.f; }
    }
    __syncthreads();
    int gi = i0 + ti, gjj = j0 + tj;
    if (gi < NTOK && gjj < NTOK) {
      bool use_s = (gi < 384) && (gjj < 384) && ((gi >> 7) == (gjj >> 7));
      const float* qrow = use_s ? &Qs[ti][0] : &Q[ti][0];
      const float* krow = use_s ? &Ks[tj][0] : &Kt[tj][0];
      float acc = 0.0f;
      #pragma unroll
      for (int d = 0; d < 64; ++d) acc += qrow[d] * krow[d];
      S[((size_t)(b * NHEAD + hd) * NTOK + gi) * NTOK + gjj] = acc * scale;
    }
  }
}

// ---------------------------------------------------------------------------
// Row softmax in place over 393 cols. One block (128 thr) per row.
// ---------------------------------------------------------------------------
__global__ __launch_bounds__(128) void softmax_kernel(float* __restrict__ S) {
  size_t row = blockIdx.x;
  float* p = S + row * NTOK;
  int tid = threadIdx.x;
  float v[4];
  float mx = -1e30f;
  #pragma unroll
  for (int r = 0; r < 4; ++r) {
    int j = tid + r * 128;
    v[r] = (j < NTOK) ? p[j] : -1e30f;
    mx = fmaxf(mx, v[r]);
  }
  for (int off = 32; off; off >>= 1) mx = fmaxf(mx, __shfl_down(mx, off));
  __shared__ float red[2];
  if ((tid & 63) == 0) red[tid >> 6] = mx;
  __syncthreads();
  mx = fmaxf(red[0], red[1]);
  __syncthreads();
  float s = 0.0f;
  #pragma unroll
  for (int r = 0; r < 4; ++r) { v[r] = expf(v[r] - mx); s += v[r]; }
  for (int off = 32; off; off >>= 1) s += __shfl_down(s, off);
  if ((tid & 63) == 0) red[tid >> 6] = s;
  __syncthreads();
  float inv = 1.0f / (red[0] + red[1]);
  #pragma unroll
  for (int r = 0; r < 4; ++r) {
    int j = tid + r * 128;
    if (j < NTOK) p[j] = v[r] * inv;
  }
}

// ---------------------------------------------------------------------------
// PV: O[b, i, h*64+d] = sum_j attn[b,h,i,j] * V[b,j,h*64+d]
// grid: (25 i-tiles, 128 bh), 256 threads; j-chunks of 32.
// ---------------------------------------------------------------------------
__global__ __launch_bounds__(256) void pv_kernel(
    const float* __restrict__ attn, const float* __restrict__ qkv,
    float* __restrict__ O) {
  int bh = blockIdx.y;
  int b = bh >> 3, hd = bh & 7;
  int i0 = blockIdx.x * 16;
  __shared__ float Al[16][33];
  __shared__ float Vl[32][64];
  int tid = threadIdx.x;
  int d = tid & 63, ig = tid >> 6;
  float acc[4] = {0.f, 0.f, 0.f, 0.f};
  int vr = tid >> 3, vc = (tid & 7) * 8;
  for (int j0 = 0; j0 < NTOK; j0 += 32) {
    __syncthreads();
    int idx = tid;
    #pragma unroll
    for (int t = 0; t < 2; ++t, idx += 256) {
      int li = idx >> 5, lj = idx & 31;
      int gi = i0 + li, gj = j0 + lj;
      Al[li][lj] = (gi < NTOK && gj < NTOK)
          ? attn[((size_t)(b * NHEAD + hd) * NTOK + gi) * NTOK + gj] : 0.0f;
    }
    {
      int gj = j0 + vr;
      if (gj < NTOK) {
        const float* vp = qkv + ((size_t)(b * NTOK + gj)) * 1536 + 1024 + hd * 64 + vc;
        #pragma unroll
        for (int t = 0; t < 8; ++t) Vl[vr][vc + t] = vp[t];
      } else {
        #pragma unroll
        for (int t = 0; t < 8; ++t) Vl[vr][vc + t] = 0.0f;
      }
    }
    __syncthreads();
    #pragma unroll
    for (int j = 0; j < 32; ++j) {
      float vv = Vl[j][d];
      #pragma unroll
      for (int r = 0; r < 4; ++r) acc[r] += Al[ig * 4 + r][j] * vv;
    }
  }
  #pragma unroll
  for (int r = 0; r < 4; ++r) {
    int i = i0 + ig * 4 + r;
    if (i < NTOK) O[((size_t)b * NTOK + i) * DMODEL + hd * 64 + d] = acc[r];
  }
}

// ---------------------------------------------------------------------------
// Final: mean-pool over tokens, LN, gen head. One block (512 thr) per batch.
// ---------------------------------------------------------------------------
__global__ __launch_bounds__(512) void final_kernel(
    const float* __restrict__ X, const float* __restrict__ gg,
    const float* __restrict__ gb, const float* __restrict__ gW,
    const float* __restrict__ gbias, float* __restrict__ out) {
  int b = blockIdx.x;
  int tid = threadIdx.x;
  const float* xb = X + (size_t)b * NTOK * DMODEL;
  float s = 0.0f;
  for (int t = 0; t < NTOK; ++t) s += xb[(size_t)t * DMODEL + tid];
  float pooled = s / (float)NTOK;
  __shared__ float red[8];
  float ss = pooled;
  for (int off = 32; off; off >>= 1) ss += __shfl_down(ss, off);
  if ((tid & 63) == 0) red[tid >> 6] = ss;
  __syncthreads();
  float mu = 0.0f;
  #pragma unroll
  for (int w = 0; w < 8; ++w) mu += red[w];
  mu *= (1.0f / DMODEL);
  __syncthreads();
  float dv = pooled - mu;
  float s2 = dv * dv;
  for (int off = 32; off; off >>= 1) s2 += __shfl_down(s2, off);
  if ((tid & 63) == 0) red[tid >> 6] = s2;
  __syncthreads();
  float var = 0.0f;
  #pragma unroll
  for (int w = 0; w < 8; ++w) var += red[w];
  var *= (1.0f / DMODEL);
  float y = dv * rsqrtf(var + 1e-5f) * gg[tid] + gb[tid];
  __shared__ float yl[DMODEL];
  yl[tid] = y;
  __syncthreads();
  if (tid < NPRED) {
    float acc = gbias[tid];
    for (int d = 0; d < DMODEL; ++d) acc += yl[d] * gW[d * NPRED + tid];
    out[b * NPRED + tid] = acc;
  }
}

// ---------------------------------------------------------------------------
extern "C" void kernel_launch(void* const* d_in, const int* in_sizes, int n_in,
                              void* d_out, int out_size, void* d_ws, size_t ws_size,
                              hipStream_t stream) {
  const float* x_in   = (const float*)d_in[0];
  const float* spec   = (const float*)d_in[1];
  const float* Wc     = (const float*)d_in[2];
  const float* bc     = (const float*)d_in[3];
  const float* Wb     = (const float*)d_in[4];
  const float* bb     = (const float*)d_in[5];
  const float* Wt     = (const float*)d_in[6];
  const float* bt     = (const float*)d_in[7];
  const float* spec_W = (const float*)d_in[8];
  const float* spec_b = (const float*)d_in[9];
  const float* ln1_g  = (const float*)d_in[10];
  const float* ln1_b  = (const float*)d_in[11];
  const float* qkv_W  = (const float*)d_in[12];
  const float* qks_W  = (const float*)d_in[13];
  const float* out_W  = (const float*)d_in[14];
  const float* out_b  = (const float*)d_in[15];
  const float* ln2_g  = (const float*)d_in[16];
  const float* ln2_b  = (const float*)d_in[17];
  const float* ff_W1  = (const float*)d_in[18];
  const float* ff_b1  = (const float*)d_in[19];
  const float* ff_W2  = (const float*)d_in[20];
  const float* ff_b2  = (const float*)d_in[21];
  const float* gen_g  = (const float*)d_in[22];
  const float* gen_bl = (const float*)d_in[23];
  const float* gen_W  = (const float*)d_in[24];
  const float* gen_b  = (const float*)d_in[25];

  float* ws = (float*)d_ws;
  // workspace layout (floats); ff1 aliases qkv+qks region (dead by then)
  float* x    = ws;                          // 6288*512  = 3,219,456
  float* h    = x + (size_t)ROWS * DMODEL;   // 3,219,456
  float* qkv  = h + (size_t)ROWS * DMODEL;   // 6288*1536 = 9,658,368
  float* qks  = qkv + (size_t)ROWS * 1536;   // 6288*1024 = 6,438,912
  float* ff1  = qkv;                         // alias: 12,877,824 <= 16,097,280
  float* o    = qks + (size_t)ROWS * 1024;   // 3,219,456
  // total: 25,755,648 floats = 103 MB

  float* out_f = (float*)d_out;

  embed_kernel<<<BATCH * NTOK, 256, 0, stream>>>(
      x_in, spec, Wc, bc, Wb, bb, Wt, bt, spec_W, spec_b, x);

  const int MB = (ROWS + 63) / 64; // 99

  for (int l = 0; l < DEPTH; ++l) {
    float* attn = out_f + 320 + (size_t)l * ATTN_PER_LAYER;

    ln_kernel<<<ROWS, 256, 0, stream>>>(x, ln1_g + l * DMODEL, ln1_b + l * DMODEL, h);

    gemm_kernel<false, false, false><<<dim3(1536 / 64, MB), 256, 0, stream>>>(
        h, qkv_W + (size_t)l * DMODEL * 1536, nullptr, nullptr, qkv, ROWS, DMODEL, 1536);
    gemm_kernel<false, false, false><<<dim3(1024 / 64, MB), 256, 0, stream>>>(
        h, qks_W + (size_t)l * DMODEL * 1024, nullptr, nullptr, qks, ROWS, DMODEL, 1024);

    scores_kernel<<<dim3(25, BATCH * NHEAD), 256, 0, stream>>>(qkv, qks, attn);
    softmax_kernel<<<BATCH * NHEAD * NTOK, 128, 0, stream>>>(attn);
    pv_kernel<<<dim3(25, BATCH * NHEAD), 256, 0, stream>>>(attn, qkv, o);

    gemm_kernel<true, true, false><<<dim3(DMODEL / 64, MB), 256, 0, stream>>>(
        o, out_W + (size_t)l * DMODEL * DMODEL, out_b + l * DMODEL, x, x, ROWS, DMODEL, DMODEL);

    ln_kernel<<<ROWS, 256, 0, stream>>>(x, ln2_g + l * DMODEL, ln2_b + l * DMODEL, h);

    gemm_kernel<true, false, true><<<dim3(FCDIM / 64, MB), 256, 0, stream>>>(
        h, ff_W1 + (size_t)l * DMODEL * FCDIM, ff_b1 + l * FCDIM, nullptr, ff1, ROWS, DMODEL, FCDIM);
    gemm_kernel<true, true, false><<<dim3(DMODEL / 64, MB), 256, 0, stream>>>(
        ff1, ff_W2 + (size_t)l * FCDIM * DMODEL, ff_b2 + l * DMODEL, x, x, ROWS, FCDIM, DMODEL);
  }

  final_kernel<<<BATCH, 512, 0, stream>>>(x, gen_g, gen_bl, gen_W, gen_b, out_f);
}

// Round 7
// 2304.617 us; speedup vs baseline: 2.0272x; 2.0272x over previous
//
#include <hip/hip_runtime.h>
#include <hip/hip_bf16.h>
#include <math.h>

// Problem constants
#define BATCH   16
#define NTOK    393            // 3*128 + 9
#define ROWS    (BATCH * NTOK) // 6288
#define MPAD    6400           // 50 * 128
#define DMODEL  512
#define NHEAD   8
#define DHEAD   64
#define FCDIM   2048
#define DEPTH   4
#define NPRED   20
#define ATTN_PER_LAYER ((size_t)BATCH * NHEAD * NTOK * NTOK) // 19,769,472

typedef _Float16 half_t;
typedef __attribute__((ext_vector_type(8))) _Float16 half8;
typedef __attribute__((ext_vector_type(4))) _Float16 half4;
typedef __attribute__((ext_vector_type(2))) _Float16 half2v;
typedef __attribute__((ext_vector_type(4))) float f32x4;

// ---------------------------------------------------------------------------
// Embedding: per-agent linear projections + sinusoidal PE + spec tokens (fp32 x)
// ---------------------------------------------------------------------------
__global__ __launch_bounds__(256) void embed_kernel(
    const float* __restrict__ x_in, const float* __restrict__ spec,
    const float* __restrict__ Wc, const float* __restrict__ bc,
    const float* __restrict__ Wb, const float* __restrict__ bb,
    const float* __restrict__ Wt, const float* __restrict__ btg,
    const float* __restrict__ specW, const float* __restrict__ specB,
    float* __restrict__ X) {
  int bt = blockIdx.x;
  int b = bt / NTOK, t = bt % NTOK;
  int tid = threadIdx.x;
  for (int d = tid; d < DMODEL; d += 256) {
    float val;
    if (t < 384) {
      int a = t >> 7, p = t & 127;
      const float* W; const float* bias; int nf, f0;
      if (a == 0)      { W = Wc; bias = bc;  nf = 9;  f0 = 0;  }
      else if (a == 1) { W = Wb; bias = bb;  nf = 12; f0 = 9;  }
      else             { W = Wt; bias = btg; nf = 8;  f0 = 21; }
      val = bias[d];
      const float* xi = x_in + ((size_t)b * 128 + p) * 29 + f0;
      for (int f = 0; f < nf; ++f) val += xi[f] * W[f * DMODEL + d];
      float iv = (float)((d >> 1) << 1);
      float div = expf(-logf(10000.0f) * iv / (float)DMODEL);
      float aa = (float)a * div, tt = (float)p * div;
      val += (d & 1) ? (cosf(aa) + cosf(tt)) : (sinf(aa) + sinf(tt));
    } else {
      int f = t - 384;
      val = spec[b * 9 + f] * specW[f * DMODEL + d] + specB[f * DMODEL + d];
    }
    X[((size_t)b * NTOK + t) * DMODEL + d] = val;
  }
}

// ---------------------------------------------------------------------------
// LayerNorm fp32 -> f16. Grid MPAD rows; rows >= ROWS write zeros (padding).
// ---------------------------------------------------------------------------
__global__ __launch_bounds__(256) void ln_kernel(
    const float* __restrict__ X, const float* __restrict__ g,
    const float* __restrict__ b, half_t* __restrict__ Y) {
  int row = blockIdx.x;
  int tid = threadIdx.x;
  if (row >= ROWS) {
    half2v z = {(half_t)0.f, (half_t)0.f};
    *(half2v*)(Y + (size_t)row * DMODEL + tid * 2) = z;
    return;
  }
  const float* xr = X + (size_t)row * DMODEL;
  float2 v = *(const float2*)(xr + tid * 2);
  float s = v.x + v.y;
  for (int off = 32; off; off >>= 1) s += __shfl_down(s, off);
  __shared__ float red[4];
  if ((tid & 63) == 0) red[tid >> 6] = s;
  __syncthreads();
  float mu = (red[0] + red[1] + red[2] + red[3]) * (1.0f / DMODEL);
  __syncthreads();
  float dx = v.x - mu, dy = v.y - mu;
  float s2 = dx * dx + dy * dy;
  for (int off = 32; off; off >>= 1) s2 += __shfl_down(s2, off);
  if ((tid & 63) == 0) red[tid >> 6] = s2;
  __syncthreads();
  float var = (red[0] + red[1] + red[2] + red[3]) * (1.0f / DMODEL);
  float rs = rsqrtf(var + 1e-5f);
  half2v o;
  o[0] = (half_t)(dx * rs * g[tid * 2]     + b[tid * 2]);
  o[1] = (half_t)(dy * rs * g[tid * 2 + 1] + b[tid * 2 + 1]);
  *(half2v*)(Y + (size_t)row * DMODEL + tid * 2) = o;
}

// ---------------------------------------------------------------------------
// Weight convert+transpose: W[K][N] fp32 -> Wt[N][K] f16. 32x32 tiles.
// ---------------------------------------------------------------------------
__global__ __launch_bounds__(256) void wconv_kernel(
    const float* __restrict__ W, half_t* __restrict__ Wt, int K, int N) {
  __shared__ float T[32][33];
  int n0 = blockIdx.x * 32, k0 = blockIdx.y * 32;
  int tx = threadIdx.x & 31, ty = threadIdx.x >> 5; // ty 0..7
  #pragma unroll
  for (int r = 0; r < 4; ++r)
    T[ty + r * 8][tx] = W[(size_t)(k0 + ty + r * 8) * N + n0 + tx];
  __syncthreads();
  #pragma unroll
  for (int r = 0; r < 4; ++r)
    Wt[(size_t)(n0 + ty + r * 8) * K + k0 + tx] = (half_t)T[tx][ty + r * 8];
}

// ---------------------------------------------------------------------------
// MFMA GEMM: C = epilogue(A[Mpad][K] @ Wt[N][K]^T). f16 in, fp32 accum.
// 128x128 tile, BK=32, 4 waves (2x2), 4x4 16x16 fragments per wave.
// OUT_F16: write f16 C [Mpad][N] (no row guard needed; buffers padded).
// else:    write fp32 C [Mreal][N], optional residual add, row-guarded.
// ---------------------------------------------------------------------------
template <bool BIAS, bool RES, bool GELU_ACT, bool OUT_F16>
__global__ __launch_bounds__(256) void mfma_gemm(
    const half_t* __restrict__ A, const half_t* __restrict__ Wt,
    const float* __restrict__ bias, const float* __restrict__ R,
    void* __restrict__ Cout, int Mreal, int K, int N) {
  __shared__ half_t As[128 * 32];
  __shared__ half_t Bs[128 * 32];
  int tid = threadIdx.x;
  int lane = tid & 63, wid = tid >> 6;
  int brow = blockIdx.y * 128;
  int bcol = blockIdx.x * 128;
  int wr = wid >> 1, wc = wid & 1;
  int l15 = lane & 15, l4 = lane >> 4;

  f32x4 acc[4][4];
  #pragma unroll
  for (int i = 0; i < 4; ++i)
    #pragma unroll
    for (int n = 0; n < 4; ++n)
      #pragma unroll
      for (int r = 0; r < 4; ++r) acc[i][n][r] = 0.0f;

  int srow = tid >> 2;           // 0..63
  int skseg = (tid & 3) * 8;     // 0,8,16,24
  const half_t* Ag = A  + (size_t)(brow + srow) * K + skseg;
  const half_t* Bg = Wt + (size_t)(bcol + srow) * K + skseg;

  for (int k0 = 0; k0 < K; k0 += 32) {
    __syncthreads();
    #pragma unroll
    for (int q = 0; q < 2; ++q) {
      int4 av = *(const int4*)(Ag + (size_t)(q * 64) * K + k0);
      int4 bv = *(const int4*)(Bg + (size_t)(q * 64) * K + k0);
      *(int4*)&As[(q * 64 + srow) * 32 + skseg] = av;
      *(int4*)&Bs[(q * 64 + srow) * 32 + skseg] = bv;
    }
    __syncthreads();
    half8 af[4], bf[4];
    #pragma unroll
    for (int i = 0; i < 4; ++i)
      af[i] = *(const half8*)&As[(wr * 64 + i * 16 + l15) * 32 + l4 * 8];
    #pragma unroll
    for (int n = 0; n < 4; ++n)
      bf[n] = *(const half8*)&Bs[(wc * 64 + n * 16 + l15) * 32 + l4 * 8];
    #pragma unroll
    for (int i = 0; i < 4; ++i)
      #pragma unroll
      for (int n = 0; n < 4; ++n)
        acc[i][n] = __builtin_amdgcn_mfma_f32_16x16x32_f16(af[i], bf[n], acc[i][n], 0, 0, 0);
  }

  // Epilogue. C/D layout: col = lane&15, row = (lane>>4)*4 + reg [m89-verified]
  #pragma unroll
  for (int i = 0; i < 4; ++i) {
    #pragma unroll
    for (int n = 0; n < 4; ++n) {
      int gcol = bcol + wc * 64 + n * 16 + l15;
      #pragma unroll
      for (int r = 0; r < 4; ++r) {
        int grow = brow + wr * 64 + i * 16 + l4 * 4 + r;
        float v = acc[i][n][r];
        if (BIAS) v += bias[gcol];
        if (GELU_ACT) v = 0.5f * v * (1.0f + erff(v * 0.70710678118f));
        if (OUT_F16) {
          ((half_t*)Cout)[(size_t)grow * N + gcol] = (half_t)v;
        } else {
          if (grow < Mreal) {
            if (RES) v += R[(size_t)grow * N + gcol];
            ((float*)Cout)[(size_t)grow * N + gcol] = v;
          }
        }
      }
    }
  }
}

// ---------------------------------------------------------------------------
// Fused scores + softmax. Block: (i-tile of 16 rows) x (b,h). Computes the
// masked-select dual dot products, softmaxes rows in LDS, writes normalized
// attn once to d_out.
// ---------------------------------------------------------------------------
__global__ __launch_bounds__(256) void scores_softmax_kernel(
    const half_t* __restrict__ qkv, const half_t* __restrict__ qks,
    float* __restrict__ Sout) {
  int bh = blockIdx.y;
  int b = bh >> 3, hd = bh & 7;
  int i0 = blockIdx.x * 16;
  __shared__ float S[16][400];
  __shared__ float Q[16][64], Qs[16][64];
  __shared__ float Kt[16][68], Ks[16][68]; // 68: bank spread for col-reads
  int tid = threadIdx.x;
  int r = tid >> 4, d4 = (tid & 15) * 4;
  {
    int gi = i0 + r;
    if (gi < NTOK) {
      half4 qv  = *(const half4*)(qkv + ((size_t)(b * NTOK + gi)) * 1536 + hd * 64 + d4);
      half4 qsv = *(const half4*)(qks + ((size_t)(b * NTOK + gi)) * 1024 + hd * 64 + d4);
      #pragma unroll
      for (int t = 0; t < 4; ++t) { Q[r][d4 + t] = (float)qv[t]; Qs[r][d4 + t] = (float)qsv[t]; }
    } else {
      #pragma unroll
      for (int t = 0; t < 4; ++t) { Q[r][d4 + t] = 0.f; Qs[r][d4 + t] = 0.f; }
    }
  }
  const float scale = 0.125f; // 64^-0.5
  int ti = tid >> 4, tj = tid & 15;
  for (int j0 = 0; j0 < NTOK; j0 += 16) {
    __syncthreads();
    int gj = j0 + r;
    if (gj < NTOK) {
      half4 kv  = *(const half4*)(qkv + ((size_t)(b * NTOK + gj)) * 1536 + 512 + hd * 64 + d4);
      half4 ksv = *(const half4*)(qks + ((size_t)(b * NTOK + gj)) * 1024 + 512 + hd * 64 + d4);
      #pragma unroll
      for (int t = 0; t < 4; ++t) { Kt[r][d4 + t] = (float)kv[t]; Ks[r][d4 + t] = (float)ksv[t]; }
    } else {
      #pragma unroll
      for (int t = 0; t < 4; ++t) { Kt[r][d4 + t] = 0.f; Ks[r][d4 + t] = 0.f; }
    }
    __syncthreads();
    int gi = i0 + ti, gjj = j0 + tj;
    bool use_s = (gi < 384) && (gjj < 384) && ((gi >> 7) == (gjj >> 7));
    const float* qrow = use_s ? &Qs[ti][0] : &Q[ti][0];
    const float* krow = use_s ? &Ks[tj][0] : &Kt[tj][0];
    float acc = 0.0f;
    #pragma unroll
    for (int d = 0; d < 64; ++d) acc += qrow[d] * krow[d];
    S[ti][j0 + tj] = acc * scale;
  }
  __syncthreads();
  // softmax: row rr handled by 16 lanes (c = lane offset within row)
  int rr = tid >> 4, c = tid & 15;
  float mx = -1e30f;
  for (int t = c; t < NTOK; t += 16) mx = fmaxf(mx, S[rr][t]);
  #pragma unroll
  for (int off = 8; off; off >>= 1) mx = fmaxf(mx, __shfl_xor(mx, off, 16));
  float sum = 0.0f;
  for (int t = c; t < NTOK; t += 16) { float e = expf(S[rr][t] - mx); S[rr][t] = e; sum += e; }
  #pragma unroll
  for (int off = 8; off; off >>= 1) sum += __shfl_xor(sum, off, 16);
  float inv = 1.0f / sum;
  int girow = i0 + rr;
  if (girow < NTOK) {
    float* dst = Sout + ((size_t)(b * NHEAD + hd) * NTOK + girow) * NTOK;
    for (int t = c; t < NTOK; t += 16) dst[t] = S[rr][t] * inv;
  }
}

// ---------------------------------------------------------------------------
// PV: O[b, i, h*64+d] = sum_j attn[b,h,i,j] * V[b,j,h*64+d]. V f16, O f16.
// ---------------------------------------------------------------------------
__global__ __launch_bounds__(256) void pv_kernel(
    const float* __restrict__ attn, const half_t* __restrict__ qkv,
    half_t* __restrict__ O) {
  int bh = blockIdx.y;
  int b = bh >> 3, hd = bh & 7;
  int i0 = blockIdx.x * 16;
  __shared__ float Al[16][33];
  __shared__ float Vl[32][64];
  int tid = threadIdx.x;
  int d = tid & 63, ig = tid >> 6;
  float acc[4] = {0.f, 0.f, 0.f, 0.f};
  int vr = tid >> 3, vc = (tid & 7) * 8;
  for (int j0 = 0; j0 < NTOK; j0 += 32) {
    __syncthreads();
    int idx = tid;
    #pragma unroll
    for (int t = 0; t < 2; ++t, idx += 256) {
      int li = idx >> 5, lj = idx & 31;
      int gi = i0 + li, gj = j0 + lj;
      Al[li][lj] = (gi < NTOK && gj < NTOK)
          ? attn[((size_t)(b * NHEAD + hd) * NTOK + gi) * NTOK + gj] : 0.0f;
    }
    {
      int gj = j0 + vr;
      if (gj < NTOK) {
        half8 vv = *(const half8*)(qkv + ((size_t)(b * NTOK + gj)) * 1536 + 1024 + hd * 64 + vc);
        #pragma unroll
        for (int t = 0; t < 8; ++t) Vl[vr][vc + t] = (float)vv[t];
      } else {
        #pragma unroll
        for (int t = 0; t < 8; ++t) Vl[vr][vc + t] = 0.0f;
      }
    }
    __syncthreads();
    #pragma unroll
    for (int j = 0; j < 32; ++j) {
      float vv = Vl[j][d];
      #pragma unroll
      for (int r = 0; r < 4; ++r) acc[r] += Al[ig * 4 + r][j] * vv;
    }
  }
  #pragma unroll
  for (int r = 0; r < 4; ++r) {
    int i = i0 + ig * 4 + r;
    if (i < NTOK) O[((size_t)b * NTOK + i) * DMODEL + hd * 64 + d] = (half_t)acc[r];
  }
}

// ---------------------------------------------------------------------------
// Final: mean-pool over tokens, LN, gen head. One block (512 thr) per batch.
// ---------------------------------------------------------------------------
__global__ __launch_bounds__(512) void final_kernel(
    const float* __restrict__ X, const float* __restrict__ gg,
    const float* __restrict__ gb, const float* __restrict__ gW,
    const float* __restrict__ gbias, float* __restrict__ out) {
  int b = blockIdx.x;
  int tid = threadIdx.x;
  const float* xb = X + (size_t)b * NTOK * DMODEL;
  float s = 0.0f;
  for (int t = 0; t < NTOK; ++t) s += xb[(size_t)t * DMODEL + tid];
  float pooled = s / (float)NTOK;
  __shared__ float red[8];
  float ss = pooled;
  for (int off = 32; off; off >>= 1) ss += __shfl_down(ss, off);
  if ((tid & 63) == 0) red[tid >> 6] = ss;
  __syncthreads();
  float mu = 0.0f;
  #pragma unroll
  for (int w = 0; w < 8; ++w) mu += red[w];
  mu *= (1.0f / DMODEL);
  __syncthreads();
  float dv = pooled - mu;
  float s2 = dv * dv;
  for (int off = 32; off; off >>= 1) s2 += __shfl_down(s2, off);
  if ((tid & 63) == 0) red[tid >> 6] = s2;
  __syncthreads();
  float var = 0.0f;
  #pragma unroll
  for (int w = 0; w < 8; ++w) var += red[w];
  var *= (1.0f / DMODEL);
  float y = dv * rsqrtf(var + 1e-5f) * gg[tid] + gb[tid];
  __shared__ float yl[DMODEL];
  yl[tid] = y;
  __syncthreads();
  if (tid < NPRED) {
    float acc = gbias[tid];
    for (int d = 0; d < DMODEL; ++d) acc += yl[d] * gW[d * NPRED + tid];
    out[b * NPRED + tid] = acc;
  }
}

// ---------------------------------------------------------------------------
extern "C" void kernel_launch(void* const* d_in, const int* in_sizes, int n_in,
                              void* d_out, int out_size, void* d_ws, size_t ws_size,
                              hipStream_t stream) {
  const float* x_in   = (const float*)d_in[0];
  const float* spec   = (const float*)d_in[1];
  const float* Wc     = (const float*)d_in[2];
  const float* bc     = (const float*)d_in[3];
  const float* Wb     = (const float*)d_in[4];
  const float* bb     = (const float*)d_in[5];
  const float* Wt     = (const float*)d_in[6];
  const float* bt     = (const float*)d_in[7];
  const float* spec_W = (const float*)d_in[8];
  const float* spec_b = (const float*)d_in[9];
  const float* ln1_g  = (const float*)d_in[10];
  const float* ln1_b  = (const float*)d_in[11];
  const float* qkv_W  = (const float*)d_in[12];
  const float* qks_W  = (const float*)d_in[13];
  const float* out_W  = (const float*)d_in[14];
  const float* out_b  = (const float*)d_in[15];
  const float* ln2_g  = (const float*)d_in[16];
  const float* ln2_b  = (const float*)d_in[17];
  const float* ff_W1  = (const float*)d_in[18];
  const float* ff_b1  = (const float*)d_in[19];
  const float* ff_W2  = (const float*)d_in[20];
  const float* ff_b2  = (const float*)d_in[21];
  const float* gen_g  = (const float*)d_in[22];
  const float* gen_bl = (const float*)d_in[23];
  const float* gen_W  = (const float*)d_in[24];
  const float* gen_b  = (const float*)d_in[25];

  // workspace carve (bytes)
  char* w = (char*)d_ws;
  float* x      = (float*)w;                    w += (size_t)ROWS * DMODEL * 4;   // 12,877,824
  half_t* h     = (half_t*)w;                   w += (size_t)MPAD * DMODEL * 2;   // 6,553,600
  half_t* qkv   = (half_t*)w;                   w += (size_t)MPAD * 1536 * 2;     // 19,660,800
  half_t* qks   = (half_t*)w;                   w += (size_t)MPAD * 1024 * 2;     // 13,107,200
  half_t* o     = (half_t*)w;                   w += (size_t)MPAD * DMODEL * 2;   // 6,553,600
  half_t* wt_qkv = (half_t*)w;                  w += (size_t)DEPTH * 1536 * 512 * 2;
  half_t* wt_qks = (half_t*)w;                  w += (size_t)DEPTH * 1024 * 512 * 2;
  half_t* wt_out = (half_t*)w;                  w += (size_t)DEPTH * 512 * 512 * 2;
  half_t* wt_ff1 = (half_t*)w;                  w += (size_t)DEPTH * 2048 * 512 * 2;
  half_t* wt_ff2 = (half_t*)w;                  w += (size_t)DEPTH * 512 * 2048 * 2;
  half_t* ff1   = qkv;  // alias: ff1 [MPAD][2048] fits in qkv+qks region

  float* out_f = (float*)d_out;

  // weight convert+transpose (every launch; same work each call)
  for (int l = 0; l < DEPTH; ++l) {
    wconv_kernel<<<dim3(1536 / 32, 512 / 32), 256, 0, stream>>>(
        qkv_W + (size_t)l * 512 * 1536, wt_qkv + (size_t)l * 1536 * 512, 512, 1536);
    wconv_kernel<<<dim3(1024 / 32, 512 / 32), 256, 0, stream>>>(
        qks_W + (size_t)l * 512 * 1024, wt_qks + (size_t)l * 1024 * 512, 512, 1024);
    wconv_kernel<<<dim3(512 / 32, 512 / 32), 256, 0, stream>>>(
        out_W + (size_t)l * 512 * 512, wt_out + (size_t)l * 512 * 512, 512, 512);
    wconv_kernel<<<dim3(2048 / 32, 512 / 32), 256, 0, stream>>>(
        ff_W1 + (size_t)l * 512 * 2048, wt_ff1 + (size_t)l * 2048 * 512, 512, 2048);
    wconv_kernel<<<dim3(512 / 32, 2048 / 32), 256, 0, stream>>>(
        ff_W2 + (size_t)l * 2048 * 512, wt_ff2 + (size_t)l * 512 * 2048, 2048, 512);
  }

  embed_kernel<<<BATCH * NTOK, 256, 0, stream>>>(
      x_in, spec, Wc, bc, Wb, bb, Wt, bt, spec_W, spec_b, x);

  for (int l = 0; l < DEPTH; ++l) {
    float* attn = out_f + 320 + (size_t)l * ATTN_PER_LAYER;

    ln_kernel<<<MPAD, 256, 0, stream>>>(x, ln1_g + l * DMODEL, ln1_b + l * DMODEL, h);

    mfma_gemm<false, false, false, true><<<dim3(1536 / 128, MPAD / 128), 256, 0, stream>>>(
        h, wt_qkv + (size_t)l * 1536 * 512, nullptr, nullptr, qkv, ROWS, 512, 1536);
    mfma_gemm<false, false, false, true><<<dim3(1024 / 128, MPAD / 128), 256, 0, stream>>>(
        h, wt_qks + (size_t)l * 1024 * 512, nullptr, nullptr, qks, ROWS, 512, 1024);

    scores_softmax_kernel<<<dim3(25, BATCH * NHEAD), 256, 0, stream>>>(qkv, qks, attn);
    pv_kernel<<<dim3(25, BATCH * NHEAD), 256, 0, stream>>>(attn, qkv, o);

    mfma_gemm<true, true, false, false><<<dim3(512 / 128, MPAD / 128), 256, 0, stream>>>(
        o, wt_out + (size_t)l * 512 * 512, out_b + l * DMODEL, x, x, ROWS, 512, 512);

    ln_kernel<<<MPAD, 256, 0, stream>>>(x, ln2_g + l * DMODEL, ln2_b + l * DMODEL, h);

    mfma_gemm<true, false, true, true><<<dim3(2048 / 128, MPAD / 128), 256, 0, stream>>>(
        h, wt_ff1 + (size_t)l * 2048 * 512, ff_b1 + l * FCDIM, nullptr, ff1, ROWS, 512, 2048);
    mfma_gemm<true, true, false, false><<<dim3(512 / 128, MPAD / 128), 256, 0, stream>>>(
        ff1, wt_ff2 + (size_t)l * 512 * 2048, ff_b2 + l * DMODEL, x, x, ROWS, 2048, 512);
  }

  final_kernel<<<BATCH, 512, 0, stream>>>(x, gen_g, gen_bl, gen_W, gen_b, out_f);
}

// Round 8
// 1540.928 us; speedup vs baseline: 3.0318x; 1.4956x over previous
//
#include <hip/hip_runtime.h>
#include <hip/hip_bf16.h>
#include <math.h>

// Problem constants
#define BATCH   16
#define NTOK    393            // 3*128 + 9
#define ROWS    (BATCH * NTOK) // 6288
#define MPAD    6400           // 50 * 128
#define DMODEL  512
#define NHEAD   8
#define DHEAD   64
#define FCDIM   2048
#define DEPTH   4
#define NPRED   20
#define ATTN_PER_LAYER ((size_t)BATCH * NHEAD * NTOK * NTOK) // 19,769,472

typedef _Float16 half_t;
typedef __attribute__((ext_vector_type(8))) _Float16 half8;
typedef __attribute__((ext_vector_type(4))) _Float16 half4;
typedef __attribute__((ext_vector_type(2))) _Float16 half2v;
typedef __attribute__((ext_vector_type(4))) float f32x4;

// ---------------------------------------------------------------------------
// Embedding: per-agent linear projections + sinusoidal PE + spec tokens (fp32 x)
// ---------------------------------------------------------------------------
__global__ __launch_bounds__(256) void embed_kernel(
    const float* __restrict__ x_in, const float* __restrict__ spec,
    const float* __restrict__ Wc, const float* __restrict__ bc,
    const float* __restrict__ Wb, const float* __restrict__ bb,
    const float* __restrict__ Wt, const float* __restrict__ btg,
    const float* __restrict__ specW, const float* __restrict__ specB,
    float* __restrict__ X) {
  int bt = blockIdx.x;
  int b = bt / NTOK, t = bt % NTOK;
  int tid = threadIdx.x;
  for (int d = tid; d < DMODEL; d += 256) {
    float val;
    if (t < 384) {
      int a = t >> 7, p = t & 127;
      const float* W; const float* bias; int nf, f0;
      if (a == 0)      { W = Wc; bias = bc;  nf = 9;  f0 = 0;  }
      else if (a == 1) { W = Wb; bias = bb;  nf = 12; f0 = 9;  }
      else             { W = Wt; bias = btg; nf = 8;  f0 = 21; }
      val = bias[d];
      const float* xi = x_in + ((size_t)b * 128 + p) * 29 + f0;
      for (int f = 0; f < nf; ++f) val += xi[f] * W[f * DMODEL + d];
      float iv = (float)((d >> 1) << 1);
      float div = expf(-logf(10000.0f) * iv / (float)DMODEL);
      float aa = (float)a * div, tt = (float)p * div;
      val += (d & 1) ? (cosf(aa) + cosf(tt)) : (sinf(aa) + sinf(tt));
    } else {
      int f = t - 384;
      val = spec[b * 9 + f] * specW[f * DMODEL + d] + specB[f * DMODEL + d];
    }
    X[((size_t)b * NTOK + t) * DMODEL + d] = val;
  }
}

// ---------------------------------------------------------------------------
// LayerNorm fp32 -> f16. Grid MPAD rows; rows >= ROWS write zeros (padding).
// ---------------------------------------------------------------------------
__global__ __launch_bounds__(256) void ln_kernel(
    const float* __restrict__ X, const float* __restrict__ g,
    const float* __restrict__ b, half_t* __restrict__ Y) {
  int row = blockIdx.x;
  int tid = threadIdx.x;
  if (row >= ROWS) {
    half2v z = {(half_t)0.f, (half_t)0.f};
    *(half2v*)(Y + (size_t)row * DMODEL + tid * 2) = z;
    return;
  }
  const float* xr = X + (size_t)row * DMODEL;
  float2 v = *(const float2*)(xr + tid * 2);
  float s = v.x + v.y;
  for (int off = 32; off; off >>= 1) s += __shfl_down(s, off);
  __shared__ float red[4];
  if ((tid & 63) == 0) red[tid >> 6] = s;
  __syncthreads();
  float mu = (red[0] + red[1] + red[2] + red[3]) * (1.0f / DMODEL);
  __syncthreads();
  float dx = v.x - mu, dy = v.y - mu;
  float s2 = dx * dx + dy * dy;
  for (int off = 32; off; off >>= 1) s2 += __shfl_down(s2, off);
  if ((tid & 63) == 0) red[tid >> 6] = s2;
  __syncthreads();
  float var = (red[0] + red[1] + red[2] + red[3]) * (1.0f / DMODEL);
  float rs = rsqrtf(var + 1e-5f);
  half2v o;
  o[0] = (half_t)(dx * rs * g[tid * 2]     + b[tid * 2]);
  o[1] = (half_t)(dy * rs * g[tid * 2 + 1] + b[tid * 2 + 1]);
  *(half2v*)(Y + (size_t)row * DMODEL + tid * 2) = o;
}

// ---------------------------------------------------------------------------
// Weight convert+transpose: W[K][N] fp32 -> Wt[N][K] f16. 32x32 tiles.
// ---------------------------------------------------------------------------
__global__ __launch_bounds__(256) void wconv_kernel(
    const float* __restrict__ W, half_t* __restrict__ Wt, int K, int N) {
  __shared__ float T[32][33];
  int n0 = blockIdx.x * 32, k0 = blockIdx.y * 32;
  int tx = threadIdx.x & 31, ty = threadIdx.x >> 5; // ty 0..7
  #pragma unroll
  for (int r = 0; r < 4; ++r)
    T[ty + r * 8][tx] = W[(size_t)(k0 + ty + r * 8) * N + n0 + tx];
  __syncthreads();
  #pragma unroll
  for (int r = 0; r < 4; ++r)
    Wt[(size_t)(n0 + ty + r * 8) * K + k0 + tx] = (half_t)T[tx][ty + r * 8];
}

// ---------------------------------------------------------------------------
// MFMA GEMM: C = epilogue(A[Mpad][K] @ Wt[N][K]^T). f16 in, fp32 accum.
// 128x128 tile, BK=32, 4 waves (2x2), 4x4 16x16 fragments per wave.
// ---------------------------------------------------------------------------
template <bool BIAS, bool RES, bool GELU_ACT, bool OUT_F16>
__global__ __launch_bounds__(256) void mfma_gemm(
    const half_t* __restrict__ A, const half_t* __restrict__ Wt,
    const float* __restrict__ bias, const float* __restrict__ R,
    void* __restrict__ Cout, int Mreal, int K, int N) {
  __shared__ half_t As[128 * 32];
  __shared__ half_t Bs[128 * 32];
  int tid = threadIdx.x;
  int lane = tid & 63, wid = tid >> 6;
  int brow = blockIdx.y * 128;
  int bcol = blockIdx.x * 128;
  int wr = wid >> 1, wc = wid & 1;
  int l15 = lane & 15, l4 = lane >> 4;

  f32x4 acc[4][4];
  #pragma unroll
  for (int i = 0; i < 4; ++i)
    #pragma unroll
    for (int n = 0; n < 4; ++n)
      #pragma unroll
      for (int r = 0; r < 4; ++r) acc[i][n][r] = 0.0f;

  int srow = tid >> 2;           // 0..63
  int skseg = (tid & 3) * 8;     // 0,8,16,24
  const half_t* Ag = A  + (size_t)(brow + srow) * K + skseg;
  const half_t* Bg = Wt + (size_t)(bcol + srow) * K + skseg;

  for (int k0 = 0; k0 < K; k0 += 32) {
    __syncthreads();
    #pragma unroll
    for (int q = 0; q < 2; ++q) {
      int4 av = *(const int4*)(Ag + (size_t)(q * 64) * K + k0);
      int4 bv = *(const int4*)(Bg + (size_t)(q * 64) * K + k0);
      *(int4*)&As[(q * 64 + srow) * 32 + skseg] = av;
      *(int4*)&Bs[(q * 64 + srow) * 32 + skseg] = bv;
    }
    __syncthreads();
    half8 af[4], bf[4];
    #pragma unroll
    for (int i = 0; i < 4; ++i)
      af[i] = *(const half8*)&As[(wr * 64 + i * 16 + l15) * 32 + l4 * 8];
    #pragma unroll
    for (int n = 0; n < 4; ++n)
      bf[n] = *(const half8*)&Bs[(wc * 64 + n * 16 + l15) * 32 + l4 * 8];
    #pragma unroll
    for (int i = 0; i < 4; ++i)
      #pragma unroll
      for (int n = 0; n < 4; ++n)
        acc[i][n] = __builtin_amdgcn_mfma_f32_16x16x32_f16(af[i], bf[n], acc[i][n], 0, 0, 0);
  }

  // Epilogue. C/D layout: col = lane&15, row = (lane>>4)*4 + reg [m89-verified]
  #pragma unroll
  for (int i = 0; i < 4; ++i) {
    #pragma unroll
    for (int n = 0; n < 4; ++n) {
      int gcol = bcol + wc * 64 + n * 16 + l15;
      #pragma unroll
      for (int r = 0; r < 4; ++r) {
        int grow = brow + wr * 64 + i * 16 + l4 * 4 + r;
        float v = acc[i][n][r];
        if (BIAS) v += bias[gcol];
        if (GELU_ACT) v = 0.5f * v * (1.0f + erff(v * 0.70710678118f));
        if (OUT_F16) {
          ((half_t*)Cout)[(size_t)grow * N + gcol] = (half_t)v;
        } else {
          if (grow < Mreal) {
            if (RES) v += R[(size_t)grow * N + gcol];
            ((float*)Cout)[(size_t)grow * N + gcol] = v;
          }
        }
      }
    }
  }
}

// ---------------------------------------------------------------------------
// V transpose: qkv V-region [b,j,h,d] f16 -> Vt[bh][64][400] f16, zero-padded
// cols >= 393. One block per bh.
// ---------------------------------------------------------------------------
__global__ __launch_bounds__(256) void vtrans_kernel(
    const half_t* __restrict__ qkv, half_t* __restrict__ Vt) {
  int bh = blockIdx.x;
  int b = bh >> 3, hd = bh & 7;
  __shared__ half_t Vl[64][72]; // 144B rows (16B aligned)
  int tid = threadIdx.x;
  for (int j0 = 0; j0 < 400; j0 += 64) {
    int jj = tid >> 2, d8 = (tid & 3) * 16;
    int gj = j0 + jj;
    if (gj < NTOK) {
      const int4* src = (const int4*)(qkv + ((size_t)(b * NTOK + gj)) * 1536 + 1024 + hd * 64 + d8);
      *(int4*)&Vl[jj][d8]     = src[0];
      *(int4*)&Vl[jj][d8 + 8] = src[1];
    } else {
      half8 z;
      #pragma unroll
      for (int t = 0; t < 8; ++t) z[t] = (half_t)0.f;
      *(half8*)&Vl[jj][d8]     = z;
      *(half8*)&Vl[jj][d8 + 8] = z;
    }
    __syncthreads();
    int d = tid >> 2, j8 = (tid & 3) * 16;
    int cj = j0 + j8;
    if (cj < 400) {
      half_t tmp[16];
      #pragma unroll
      for (int k = 0; k < 16; ++k) tmp[k] = Vl[j8 + k][d];
      half_t* dst = Vt + ((size_t)bh * 64 + d) * 400 + cj;
      *(int4*)dst       = *(int4*)&tmp[0];
      *(int4*)(dst + 8) = *(int4*)&tmp[8];
    }
    __syncthreads();
  }
}

// ---------------------------------------------------------------------------
// Fused attention: per (32-row i-tile, bh). MFMA scores with per-16x16-tile
// mask select (block boundaries are 16-aligned), softmax in LDS, fp32 attn
// write to d_out, MFMA PV from Vt. 4 waves: wave w -> rows (w>>1)*16,
// j/d parity (w&1).
// ---------------------------------------------------------------------------
__global__ __launch_bounds__(256) void fused_attn_kernel(
    const half_t* __restrict__ qkv, const half_t* __restrict__ qks,
    const half_t* __restrict__ Vt, float* __restrict__ Sout,
    half_t* __restrict__ O) {
  int bh = blockIdx.y;
  int b = bh >> 3, hd = bh & 7;
  int i0 = blockIdx.x * 32;
  __shared__ float S[32][400];
  __shared__ float inv[32];
  int tid = threadIdx.x, lane = tid & 63, wid = tid >> 6;
  int r = wid >> 1, cpar = wid & 1;
  int l15 = lane & 15, l4 = lane >> 4;

  // Per-wave Q/Qs A-fragments (16 rows) loaded straight from global.
  int qrow = i0 + r * 16 + l15;
  half8 qf[2], qsf[2];
  if (qrow < NTOK) {
    const half_t* qp  = qkv + ((size_t)(b * NTOK + qrow)) * 1536 + hd * 64 + l4 * 8;
    const half_t* qsp = qks + ((size_t)(b * NTOK + qrow)) * 1024 + hd * 64 + l4 * 8;
    qf[0]  = *(const half8*)qp;        qf[1]  = *(const half8*)(qp + 32);
    qsf[0] = *(const half8*)qsp;       qsf[1] = *(const half8*)(qsp + 32);
  } else {
    #pragma unroll
    for (int t = 0; t < 8; ++t) {
      qf[0][t] = (half_t)0.f; qf[1][t] = (half_t)0.f;
      qsf[0][t] = (half_t)0.f; qsf[1][t] = (half_t)0.f;
    }
  }
  const float scale = 0.125f; // 64^-0.5
  int i0t = i0 + r * 16;

  // Scores: this wave handles j-tiles of its parity.
  for (int jt = cpar; jt < 25; jt += 2) {
    int j0 = jt * 16;
    bool use_s = (i0t < 384) && (j0 < 384) && ((i0t >> 7) == (j0 >> 7));
    int krow = j0 + l15;
    half8 kf0, kf1;
    if (krow < NTOK) {
      const half_t* kp = use_s
          ? (qks + ((size_t)(b * NTOK + krow)) * 1024 + 512 + hd * 64 + l4 * 8)
          : (qkv + ((size_t)(b * NTOK + krow)) * 1536 + 512 + hd * 64 + l4 * 8);
      kf0 = *(const half8*)kp;
      kf1 = *(const half8*)(kp + 32);
    } else {
      #pragma unroll
      for (int t = 0; t < 8; ++t) { kf0[t] = (half_t)0.f; kf1[t] = (half_t)0.f; }
    }
    f32x4 acc = {0.f, 0.f, 0.f, 0.f};
    acc = __builtin_amdgcn_mfma_f32_16x16x32_f16(use_s ? qsf[0] : qf[0], kf0, acc, 0, 0, 0);
    acc = __builtin_amdgcn_mfma_f32_16x16x32_f16(use_s ? qsf[1] : qf[1], kf1, acc, 0, 0, 0);
    #pragma unroll
    for (int t = 0; t < 4; ++t)
      S[r * 16 + l4 * 4 + t][j0 + l15] = acc[t] * scale;
  }
  __syncthreads();

  // Softmax: 8 threads per row.
  {
    int row = tid >> 3, sub = tid & 7;
    float mx = -1e30f;
    for (int c = sub; c < NTOK; c += 8) mx = fmaxf(mx, S[row][c]);
    mx = fmaxf(mx, __shfl_xor(mx, 1));
    mx = fmaxf(mx, __shfl_xor(mx, 2));
    mx = fmaxf(mx, __shfl_xor(mx, 4));
    float sum = 0.0f;
    for (int c = sub; c < NTOK; c += 8) {
      float e = __expf(S[row][c] - mx);
      S[row][c] = e;
      sum += e;
    }
    sum += __shfl_xor(sum, 1);
    sum += __shfl_xor(sum, 2);
    sum += __shfl_xor(sum, 4);
    if (sub == 0) inv[row] = 1.0f / sum;
  }
  __syncthreads();

  // Write normalized attn to d_out (fp32), coalesced per row.
  for (int rr = 0; rr < 32; ++rr) {
    int gi = i0 + rr;
    if (gi >= NTOK) break;
    float iv = inv[rr];
    float* dst = Sout + ((size_t)bh * NTOK + gi) * NTOK;
    for (int c = tid; c < NTOK; c += 256) dst[c] = S[rr][c] * iv;
  }

  // PV via MFMA: wave computes rows r*16..+16, d-tiles cpar*32 + {0,16}.
  f32x4 oacc[2];
  #pragma unroll
  for (int dt = 0; dt < 2; ++dt)
    #pragma unroll
    for (int t = 0; t < 4; ++t) oacc[dt][t] = 0.0f;
  int arow = r * 16 + l15;
  float aiv = inv[arow];
  for (int kc = 0; kc < 13; ++kc) {
    int k0 = kc * 32;
    bool lvalid = (k0 + l4 * 8) < 400; // last chunk: lanes with k>=400 zeroed
    half8 pa;
    if (lvalid) {
      #pragma unroll
      for (int t = 0; t < 8; ++t)
        pa[t] = (half_t)(S[arow][k0 + l4 * 8 + t] * aiv);
    } else {
      #pragma unroll
      for (int t = 0; t < 8; ++t) pa[t] = (half_t)0.f;
    }
    #pragma unroll
    for (int dt = 0; dt < 2; ++dt) {
      int d0 = cpar * 32 + dt * 16;
      half8 vb;
      if (lvalid) {
        vb = *(const half8*)(Vt + ((size_t)bh * 64 + d0 + l15) * 400 + k0 + l4 * 8);
      } else {
        #pragma unroll
        for (int t = 0; t < 8; ++t) vb[t] = (half_t)0.f;
      }
      oacc[dt] = __builtin_amdgcn_mfma_f32_16x16x32_f16(pa, vb, oacc[dt], 0, 0, 0);
    }
  }
  #pragma unroll
  for (int dt = 0; dt < 2; ++dt) {
    int d0 = cpar * 32 + dt * 16;
    #pragma unroll
    for (int t = 0; t < 4; ++t) {
      int i = i0 + r * 16 + l4 * 4 + t;
      if (i < NTOK)
        O[((size_t)(b * NTOK + i)) * DMODEL + hd * 64 + d0 + l15] = (half_t)oacc[dt][t];
    }
  }
}

// ---------------------------------------------------------------------------
// Final: mean-pool over tokens, LN, gen head. One block (512 thr) per batch.
// ---------------------------------------------------------------------------
__global__ __launch_bounds__(512) void final_kernel(
    const float* __restrict__ X, const float* __restrict__ gg,
    const float* __restrict__ gb, const float* __restrict__ gW,
    const float* __restrict__ gbias, float* __restrict__ out) {
  int b = blockIdx.x;
  int tid = threadIdx.x;
  const float* xb = X + (size_t)b * NTOK * DMODEL;
  float s = 0.0f;
  for (int t = 0; t < NTOK; ++t) s += xb[(size_t)t * DMODEL + tid];
  float pooled = s / (float)NTOK;
  __shared__ float red[8];
  float ss = pooled;
  for (int off = 32; off; off >>= 1) ss += __shfl_down(ss, off);
  if ((tid & 63) == 0) red[tid >> 6] = ss;
  __syncthreads();
  float mu = 0.0f;
  #pragma unroll
  for (int w = 0; w < 8; ++w) mu += red[w];
  mu *= (1.0f / DMODEL);
  __syncthreads();
  float dv = pooled - mu;
  float s2 = dv * dv;
  for (int off = 32; off; off >>= 1) s2 += __shfl_down(s2, off);
  if ((tid & 63) == 0) red[tid >> 6] = s2;
  __syncthreads();
  float var = 0.0f;
  #pragma unroll
  for (int w = 0; w < 8; ++w) var += red[w];
  var *= (1.0f / DMODEL);
  float y = dv * rsqrtf(var + 1e-5f) * gg[tid] + gb[tid];
  __shared__ float yl[DMODEL];
  yl[tid] = y;
  __syncthreads();
  if (tid < NPRED) {
    float acc = gbias[tid];
    for (int d = 0; d < DMODEL; ++d) acc += yl[d] * gW[d * NPRED + tid];
    out[b * NPRED + tid] = acc;
  }
}

// ---------------------------------------------------------------------------
extern "C" void kernel_launch(void* const* d_in, const int* in_sizes, int n_in,
                              void* d_out, int out_size, void* d_ws, size_t ws_size,
                              hipStream_t stream) {
  const float* x_in   = (const float*)d_in[0];
  const float* spec   = (const float*)d_in[1];
  const float* Wc     = (const float*)d_in[2];
  const float* bc     = (const float*)d_in[3];
  const float* Wb     = (const float*)d_in[4];
  const float* bb     = (const float*)d_in[5];
  const float* Wt     = (const float*)d_in[6];
  const float* bt     = (const float*)d_in[7];
  const float* spec_W = (const float*)d_in[8];
  const float* spec_b = (const float*)d_in[9];
  const float* ln1_g  = (const float*)d_in[10];
  const float* ln1_b  = (const float*)d_in[11];
  const float* qkv_W  = (const float*)d_in[12];
  const float* qks_W  = (const float*)d_in[13];
  const float* out_W  = (const float*)d_in[14];
  const float* out_b  = (const float*)d_in[15];
  const float* ln2_g  = (const float*)d_in[16];
  const float* ln2_b  = (const float*)d_in[17];
  const float* ff_W1  = (const float*)d_in[18];
  const float* ff_b1  = (const float*)d_in[19];
  const float* ff_W2  = (const float*)d_in[20];
  const float* ff_b2  = (const float*)d_in[21];
  const float* gen_g  = (const float*)d_in[22];
  const float* gen_bl = (const float*)d_in[23];
  const float* gen_W  = (const float*)d_in[24];
  const float* gen_b  = (const float*)d_in[25];

  // workspace carve (bytes)
  char* w = (char*)d_ws;
  float* x      = (float*)w;                    w += (size_t)ROWS * DMODEL * 4;
  half_t* h     = (half_t*)w;                   w += (size_t)MPAD * DMODEL * 2;   // also aliased as Vt
  half_t* qkv   = (half_t*)w;                   w += (size_t)MPAD * 1536 * 2;
  half_t* qks   = (half_t*)w;                   w += (size_t)MPAD * 1024 * 2;
  half_t* o     = (half_t*)w;                   w += (size_t)MPAD * DMODEL * 2;
  half_t* wt_qkv = (half_t*)w;                  w += (size_t)DEPTH * 1536 * 512 * 2;
  half_t* wt_qks = (half_t*)w;                  w += (size_t)DEPTH * 1024 * 512 * 2;
  half_t* wt_out = (half_t*)w;                  w += (size_t)DEPTH * 512 * 512 * 2;
  half_t* wt_ff1 = (half_t*)w;                  w += (size_t)DEPTH * 2048 * 512 * 2;
  half_t* wt_ff2 = (half_t*)w;                  w += (size_t)DEPTH * 512 * 2048 * 2;
  half_t* ff1   = qkv;   // alias: ff1 [MPAD][2048] fits in qkv+qks region
  half_t* Vt    = h;     // alias: Vt [128][64][400] f16 == h size exactly; h dead
                         // between qks-GEMM and ln2.

  float* out_f = (float*)d_out;

  // weight convert+transpose (every launch; same work each call)
  for (int l = 0; l < DEPTH; ++l) {
    wconv_kernel<<<dim3(1536 / 32, 512 / 32), 256, 0, stream>>>(
        qkv_W + (size_t)l * 512 * 1536, wt_qkv + (size_t)l * 1536 * 512, 512, 1536);
    wconv_kernel<<<dim3(1024 / 32, 512 / 32), 256, 0, stream>>>(
        qks_W + (size_t)l * 512 * 1024, wt_qks + (size_t)l * 1024 * 512, 512, 1024);
    wconv_kernel<<<dim3(512 / 32, 512 / 32), 256, 0, stream>>>(
        out_W + (size_t)l * 512 * 512, wt_out + (size_t)l * 512 * 512, 512, 512);
    wconv_kernel<<<dim3(2048 / 32, 512 / 32), 256, 0, stream>>>(
        ff_W1 + (size_t)l * 512 * 2048, wt_ff1 + (size_t)l * 2048 * 512, 512, 2048);
    wconv_kernel<<<dim3(512 / 32, 2048 / 32), 256, 0, stream>>>(
        ff_W2 + (size_t)l * 2048 * 512, wt_ff2 + (size_t)l * 512 * 2048, 2048, 512);
  }

  embed_kernel<<<BATCH * NTOK, 256, 0, stream>>>(
      x_in, spec, Wc, bc, Wb, bb, Wt, bt, spec_W, spec_b, x);

  for (int l = 0; l < DEPTH; ++l) {
    float* attn = out_f + 320 + (size_t)l * ATTN_PER_LAYER;

    ln_kernel<<<MPAD, 256, 0, stream>>>(x, ln1_g + l * DMODEL, ln1_b + l * DMODEL, h);

    mfma_gemm<false, false, false, true><<<dim3(1536 / 128, MPAD / 128), 256, 0, stream>>>(
        h, wt_qkv + (size_t)l * 1536 * 512, nullptr, nullptr, qkv, ROWS, 512, 1536);
    mfma_gemm<false, false, false, true><<<dim3(1024 / 128, MPAD / 128), 256, 0, stream>>>(
        h, wt_qks + (size_t)l * 1024 * 512, nullptr, nullptr, qks, ROWS, 512, 1024);

    // h is dead now: reuse as Vt
    vtrans_kernel<<<BATCH * NHEAD, 256, 0, stream>>>(qkv, Vt);
    fused_attn_kernel<<<dim3(13, BATCH * NHEAD), 256, 0, stream>>>(
        qkv, qks, Vt, attn, o);

    mfma_gemm<true, true, false, false><<<dim3(512 / 128, MPAD / 128), 256, 0, stream>>>(
        o, wt_out + (size_t)l * 512 * 512, out_b + l * DMODEL, x, x, ROWS, 512, 512);

    ln_kernel<<<MPAD, 256, 0, stream>>>(x, ln2_g + l * DMODEL, ln2_b + l * DMODEL, h);

    mfma_gemm<true, false, true, true><<<dim3(2048 / 128, MPAD / 128), 256, 0, stream>>>(
        h, wt_ff1 + (size_t)l * 2048 * 512, ff_b1 + l * FCDIM, nullptr, ff1, ROWS, 512, 2048);
    mfma_gemm<true, true, false, false><<<dim3(512 / 128, MPAD / 128), 256, 0, stream>>>(
        ff1, wt_ff2 + (size_t)l * 512 * 2048, ff_b2 + l * DMODEL, x, x, ROWS, 2048, 512);
  }

  final_kernel<<<BATCH, 512, 0, stream>>>(x, gen_g, gen_bl, gen_W, gen_b, out_f);
}